// Round 1
// baseline (709.645 us; speedup 1.0000x reference)
//
#include <hip/hip_runtime.h>

typedef unsigned short ushort_t;
typedef __bf16  bf16x8 __attribute__((ext_vector_type(8)));
typedef float   f32x4  __attribute__((ext_vector_type(4)));
typedef unsigned short u16x8 __attribute__((ext_vector_type(8)));

#define MFMA16(a,b,c) __builtin_amdgcn_mfma_f32_16x16x32_bf16((a),(b),(c),0,0,0)

static __device__ __forceinline__ ushort_t f2bf(float f){
  union{float f; unsigned u;} x; x.f = f;
  unsigned r = x.u + 0x7fffu + ((x.u>>16)&1u);
  return (ushort_t)(r>>16);
}
static __device__ __forceinline__ float bf2f(ushort_t b){
  union{unsigned u; float f;} x; x.u = ((unsigned)b)<<16; return x.f;
}
static __device__ __forceinline__ bf16x8 ldg_bf8(const ushort_t* p, bool valid){
  u16x8 r = {0,0,0,0,0,0,0,0};
  if(valid) r = *(const u16x8*)p;
  return __builtin_bit_cast(bf16x8, r);
}
static __device__ __forceinline__ bf16x8 ldg_bf8u(const ushort_t* p){
  u16x8 r = *(const u16x8*)p;
  return __builtin_bit_cast(bf16x8, r);
}
static __device__ __forceinline__ bf16x8 lds_bf8(const ushort_t* p){
  u16x8 r = *(const u16x8*)p;
  return __builtin_bit_cast(bf16x8, r);
}

// ---------------------------------------------------------------- weights ^T
// qkvT[n(768)][k(192)], wlT[n(256)][tap(9)][k(256)], woT[n(192)][k(256)]
__global__ __launch_bounds__(256) void transpose_w_kernel(
    const float* __restrict__ Wq, const float* __restrict__ Wk,
    const float* __restrict__ Wv, const float* __restrict__ Wl,
    const float* __restrict__ Wo,
    ushort_t* __restrict__ qkvT, ushort_t* __restrict__ wlT,
    ushort_t* __restrict__ woT)
{
  int idx = blockIdx.x*256 + threadIdx.x;
  if(idx < 147456){
    int n = idx/192, kk = idx%192;
    const float* W = (n < 256) ? Wq : ((n < 512) ? Wk : Wv);
    qkvT[idx] = f2bf(W[kk*256 + (n & 255)]);
  } else if(idx < 147456 + 589824){
    int t2 = idx - 147456;
    int n = t2/2304, r = t2%2304;          // r = tap*256 + k
    wlT[t2] = f2bf(Wl[(size_t)r*256 + n]);
  } else if(idx < 147456 + 589824 + 49152){
    int t3 = idx - 737280;
    int col = t3/256, kk = t3%256;
    woT[t3] = f2bf(Wo[kk*192 + col]);
  }
}

// ---------------------------------------------------------------- qkv GEMM
// C[100352,256] = X[100352,192] @ W[192,256]  (per which in {q,k,v})
__global__ __launch_bounds__(256) void qkv_kernel(
    const float* __restrict__ x, const ushort_t* __restrict__ WT,
    ushort_t* __restrict__ q, ushort_t* __restrict__ kbuf,
    ushort_t* __restrict__ vbuf)
{
  __shared__ ushort_t aLds[128*192];
  const int m0 = blockIdx.x * 128;
  const int which = blockIdx.y;
  ushort_t* O = (which==0) ? q : ((which==1) ? kbuf : vbuf);
  const int tid = threadIdx.x;
  // stage A (fp32 -> bf16, XOR swizzle on 16B chunks)
  #pragma unroll
  for(int it=0; it<12; ++it){
    int c = tid + it*256;
    int row = c/24, cc = c%24;
    const float* src = x + (size_t)(m0+row)*192 + cc*8;
    float4 f0 = *(const float4*)src;
    float4 f1 = *(const float4*)(src+4);
    u16x8 o;
    o[0]=f2bf(f0.x); o[1]=f2bf(f0.y); o[2]=f2bf(f0.z); o[3]=f2bf(f0.w);
    o[4]=f2bf(f1.x); o[5]=f2bf(f1.y); o[6]=f2bf(f1.z); o[7]=f2bf(f1.w);
    int off = (row*192 + cc*8) ^ ((row&7)<<3);
    *(u16x8*)&aLds[off] = o;
  }
  __syncthreads();
  const int l = tid & 63, w = tid >> 6;
  const int wm = w>>1, wn = w&1, lr = l&15, g = l>>4;
  f32x4 acc[4][8];
  #pragma unroll
  for(int mi=0;mi<4;++mi)
    #pragma unroll
    for(int nj=0;nj<8;++nj){ f32x4 z={0.f,0.f,0.f,0.f}; acc[mi][nj]=z; }
  #pragma unroll
  for(int ks=0; ks<6; ++ks){
    bf16x8 af[4];
    #pragma unroll
    for(int mi=0;mi<4;++mi){
      int row = wm*64 + mi*16 + lr;
      af[mi] = lds_bf8(&aLds[(row*192 + ks*32 + g*8) ^ ((row&7)<<3)]);
    }
    #pragma unroll
    for(int nj=0;nj<8;++nj){
      int col = wn*128 + nj*16 + lr;
      bf16x8 bfr = ldg_bf8u(WT + (size_t)(which*256 + col)*192 + ks*32 + g*8);
      #pragma unroll
      for(int mi=0;mi<4;++mi) acc[mi][nj] = MFMA16(af[mi], bfr, acc[mi][nj]);
    }
  }
  #pragma unroll
  for(int mi=0;mi<4;++mi)
    #pragma unroll
    for(int nj=0;nj<8;++nj){
      int col = wn*128 + nj*16 + lr;
      #pragma unroll
      for(int i=0;i<4;++i){
        int row = wm*64 + mi*16 + g*4 + i;
        O[(size_t)(m0+row)*256 + col] = f2bf(acc[mi][nj][i]);
      }
    }
}

// ---------------------------------------------------------------- 3x3 conv
// local[p][n] = sum_{tap,k} v(p + shift(tap))[k] * Wl[tap][k][n] + b_local[n]
__global__ __launch_bounds__(256) void conv_kernel(
    const ushort_t* __restrict__ v, const ushort_t* __restrict__ WlT,
    const float* __restrict__ b_local, ushort_t* __restrict__ local_out)
{
  const int m0 = blockIdx.x*128;
  const int n0 = blockIdx.y*128;
  const int tid = threadIdx.x;
  const int l = tid&63, w=tid>>6, wm=w>>1, wn=w&1, lr=l&15, g=l>>4;
  int py[4], px[4], pp[4];
  #pragma unroll
  for(int mi=0;mi<4;++mi){
    int p = m0 + wm*64 + mi*16 + lr;
    pp[mi] = p;
    int rem = p % 3136;
    py[mi] = rem / 56;
    px[mi] = rem % 56;
  }
  f32x4 acc[4][4];
  #pragma unroll
  for(int mi=0;mi<4;++mi)
    #pragma unroll
    for(int nj=0;nj<4;++nj){ f32x4 z={0.f,0.f,0.f,0.f}; acc[mi][nj]=z; }
  for(int tap=0; tap<9; ++tap){
    int dy = tap/3 - 1, dx = tap%3 - 1;
    const ushort_t* abase[4]; bool aval[4];
    #pragma unroll
    for(int mi=0;mi<4;++mi){
      int yy = py[mi]+dy, xx = px[mi]+dx;
      aval[mi] = ((unsigned)yy < 56u) && ((unsigned)xx < 56u);
      abase[mi] = v + (size_t)(pp[mi] + dy*56 + dx)*256;
    }
    #pragma unroll
    for(int ks=0; ks<8; ++ks){
      bf16x8 af[4];
      #pragma unroll
      for(int mi=0;mi<4;++mi) af[mi] = ldg_bf8(abase[mi] + ks*32 + g*8, aval[mi]);
      #pragma unroll
      for(int nj=0;nj<4;++nj){
        int col = n0 + wn*64 + nj*16 + lr;
        bf16x8 bfr = ldg_bf8u(WlT + (size_t)col*2304 + tap*256 + ks*32 + g*8);
        #pragma unroll
        for(int mi=0;mi<4;++mi) acc[mi][nj] = MFMA16(af[mi], bfr, acc[mi][nj]);
      }
    }
  }
  #pragma unroll
  for(int nj=0;nj<4;++nj){
    int col = n0 + wn*64 + nj*16 + lr;
    float bb = b_local[col];
    #pragma unroll
    for(int mi=0;mi<4;++mi)
      #pragma unroll
      for(int i=0;i<4;++i){
        int p = m0 + wm*64 + mi*16 + g*4 + i;
        local_out[(size_t)p*256 + col] = f2bf(acc[mi][nj][i] + bb);
      }
  }
}

// ---------------------------------------------------------------- attention
// one wave per (window, head); 49 padded to 64
__global__ __launch_bounds__(256) void attn_kernel(
    const ushort_t* __restrict__ q, const ushort_t* __restrict__ k,
    const ushort_t* __restrict__ v, ushort_t* __restrict__ out)
{
  __shared__ ushort_t pLds[4*64*64];
  __shared__ ushort_t vLds[4*32*64];
  const int tid = threadIdx.x;
  const int w = tid>>6, l = tid&63, lr = l&15, g = l>>4;
  const int gid = blockIdx.x*4 + w;
  const int win = gid>>3, head = gid&7;
  const int b = win>>6, rem = win&63, wy = rem>>3, wx = rem&7;
  const size_t base = (size_t)b*3136 + wy*7*56 + wx*7;
  ushort_t* pl = pLds + w*4096;
  ushort_t* vl = vLds + w*2048;
  // stage V^T[d(32)][p(64)] bf16, swizzled, zero-padded
  {
    int p = l;
    bool valid = p < 49;
    const ushort_t* vp = v + (base + (p/7)*56 + (p%7))*256 + head*32;
    #pragma unroll
    for(int d0=0; d0<32; d0+=8){
      u16x8 rv = {0,0,0,0,0,0,0,0};
      if(valid) rv = *(const u16x8*)(vp + d0);
      #pragma unroll
      for(int j=0;j<8;++j){
        int d = d0+j;
        vl[(d*64 + p) ^ ((d&7)<<3)] = valid ? rv[j] : (ushort_t)0;
      }
    }
  }
  // QK^T (K=32, one mfma per tile)
  f32x4 dot[4][4];
  #pragma unroll
  for(int mi=0;mi<4;++mi)
    #pragma unroll
    for(int nj=0;nj<4;++nj){ f32x4 z={0.f,0.f,0.f,0.f}; dot[mi][nj]=z; }
  bf16x8 qf[4], kf[4];
  #pragma unroll
  for(int t=0;t<4;++t){
    int p = t*16 + lr; bool valid = p<49;
    size_t pix = base + (p/7)*56 + (p%7);
    qf[t] = ldg_bf8(q + pix*256 + head*32 + g*8, valid);
    kf[t] = ldg_bf8(k + pix*256 + head*32 + g*8, valid);
  }
  #pragma unroll
  for(int mi=0;mi<4;++mi)
    #pragma unroll
    for(int nj=0;nj<4;++nj)
      dot[mi][nj] = MFMA16(qf[mi], kf[nj], dot[mi][nj]);
  // softmax over rows (cols >=49 masked), write P bf16 to LDS
  const float sc = 0.17677669529663687f * 1.4426950408889634f; // scale*log2e
  float rs[4][4];
  #pragma unroll
  for(int mi=0;mi<4;++mi){
    #pragma unroll
    for(int i=0;i<4;++i){
      float m = -1e30f;
      #pragma unroll
      for(int nj=0;nj<4;++nj){
        int col = nj*16 + lr;
        if(col < 49) m = fmaxf(m, dot[mi][nj][i]);
      }
      m = fmaxf(m, __shfl_xor(m,1));
      m = fmaxf(m, __shfl_xor(m,2));
      m = fmaxf(m, __shfl_xor(m,4));
      m = fmaxf(m, __shfl_xor(m,8));
      float e[4]; float s = 0.f;
      #pragma unroll
      for(int nj=0;nj<4;++nj){
        int col = nj*16 + lr;
        e[nj] = (col < 49) ? exp2f((dot[mi][nj][i]-m)*sc) : 0.f;
        s += e[nj];
      }
      s += __shfl_xor(s,1); s += __shfl_xor(s,2);
      s += __shfl_xor(s,4); s += __shfl_xor(s,8);
      rs[mi][i] = s;
      int row = mi*16 + g*4 + i;
      #pragma unroll
      for(int nj=0;nj<4;++nj){
        int col = nj*16 + lr;
        pl[(row*64 + col) ^ ((row&7)<<3)] = f2bf(e[nj]);
      }
    }
  }
  __syncthreads();
  // PV: (64x64)*(64x32)
  f32x4 o[4][2];
  #pragma unroll
  for(int mi=0;mi<4;++mi)
    #pragma unroll
    for(int nj=0;nj<2;++nj){ f32x4 z={0.f,0.f,0.f,0.f}; o[mi][nj]=z; }
  #pragma unroll
  for(int ks=0;ks<2;++ks){
    bf16x8 pa[4];
    #pragma unroll
    for(int mi=0;mi<4;++mi){
      int row = mi*16 + lr;
      pa[mi] = lds_bf8(&pl[(row*64 + ks*32 + g*8) ^ ((row&7)<<3)]);
    }
    #pragma unroll
    for(int nj=0;nj<2;++nj){
      int d = nj*16 + lr;
      bf16x8 vb = lds_bf8(&vl[(d*64 + ks*32 + g*8) ^ ((d&7)<<3)]);
      #pragma unroll
      for(int mi=0;mi<4;++mi) o[mi][nj] = MFMA16(pa[mi], vb, o[mi][nj]);
    }
  }
  #pragma unroll
  for(int mi=0;mi<4;++mi){
    #pragma unroll
    for(int i=0;i<4;++i){
      int row = mi*16 + g*4 + i;
      if(row < 49){
        size_t pix = base + (row/7)*56 + (row%7);
        float inv = 1.0f / rs[mi][i];
        #pragma unroll
        for(int nj=0;nj<2;++nj){
          out[pix*256 + head*32 + nj*16 + lr] = f2bf(o[mi][nj][i] * inv);
        }
      }
    }
  }
}

// ---------------------------------------------------------------- out proj
// out[100352,192] = (attn+local)[100352,256] @ Wout[256,192] + b_out
__global__ __launch_bounds__(256) void outproj_kernel(
    const ushort_t* __restrict__ attn, const ushort_t* __restrict__ local,
    const ushort_t* __restrict__ WoT, const float* __restrict__ b_out,
    float* __restrict__ out)
{
  __shared__ ushort_t aLds[128*256];
  const int m0 = blockIdx.x*128;
  const int tid = threadIdx.x;
  #pragma unroll
  for(int it=0; it<16; ++it){
    int c = tid + it*256;
    int row = c >> 5, cc = c & 31;
    size_t off = (size_t)(m0+row)*256 + cc*8;
    u16x8 a = *(const u16x8*)(attn + off);
    u16x8 bl = *(const u16x8*)(local + off);
    u16x8 o;
    #pragma unroll
    for(int j=0;j<8;++j) o[j] = f2bf(bf2f(a[j]) + bf2f(bl[j]));
    *(u16x8*)&aLds[(row*256 + cc*8) ^ ((row&7)<<3)] = o;
  }
  __syncthreads();
  const int l = tid&63, w = tid>>6, wm=w>>1, wn=w&1, lr=l&15, g=l>>4;
  f32x4 acc[4][6];
  #pragma unroll
  for(int mi=0;mi<4;++mi)
    #pragma unroll
    for(int nj=0;nj<6;++nj){ f32x4 z={0.f,0.f,0.f,0.f}; acc[mi][nj]=z; }
  #pragma unroll
  for(int ks=0;ks<8;++ks){
    bf16x8 af[4];
    #pragma unroll
    for(int mi=0;mi<4;++mi){
      int row = wm*64 + mi*16 + lr;
      af[mi] = lds_bf8(&aLds[(row*256 + ks*32 + g*8) ^ ((row&7)<<3)]);
    }
    #pragma unroll
    for(int nj=0;nj<6;++nj){
      int col = wn*96 + nj*16 + lr;
      bf16x8 bfr = ldg_bf8u(WoT + (size_t)col*256 + ks*32 + g*8);
      #pragma unroll
      for(int mi=0;mi<4;++mi) acc[mi][nj] = MFMA16(af[mi], bfr, acc[mi][nj]);
    }
  }
  #pragma unroll
  for(int nj=0;nj<6;++nj){
    int col = wn*96 + nj*16 + lr;
    float bb = b_out[col];
    #pragma unroll
    for(int mi=0;mi<4;++mi)
      #pragma unroll
      for(int i=0;i<4;++i){
        int row = wm*64 + mi*16 + g*4 + i;
        out[(size_t)(m0+row)*192 + col] = acc[mi][nj][i] + bb;
      }
  }
}

extern "C" void kernel_launch(void* const* d_in, const int* in_sizes, int n_in,
                              void* d_out, int out_size, void* d_ws, size_t ws_size,
                              hipStream_t stream)
{
  const float* x  = (const float*)d_in[0];
  const float* Wq = (const float*)d_in[1];
  const float* Wk = (const float*)d_in[2];
  const float* Wv = (const float*)d_in[3];
  const float* Wl = (const float*)d_in[4];
  const float* bl = (const float*)d_in[5];
  const float* Wo = (const float*)d_in[6];
  const float* bo = (const float*)d_in[7];
  float* out = (float*)d_out;
  char* ws = (char*)d_ws;
  // workspace layout (bytes), all 16B aligned; total ~258.5 MB
  ushort_t* q    = (ushort_t*)(ws);
  ushort_t* kbuf = (ushort_t*)(ws + 51380224);
  ushort_t* vbuf = (ushort_t*)(ws + 102760448);
  ushort_t* attn = (ushort_t*)(ws + 154140672);
  ushort_t* locl = (ushort_t*)(ws + 205520896);
  ushort_t* qkvT = (ushort_t*)(ws + 256901120);
  ushort_t* wlT  = (ushort_t*)(ws + 257196032);
  ushort_t* woT  = (ushort_t*)(ws + 258375680);

  transpose_w_kernel<<<3072, 256, 0, stream>>>(Wq, Wk, Wv, Wl, Wo, qkvT, wlT, woT);
  qkv_kernel<<<dim3(784,3), 256, 0, stream>>>(x, qkvT, q, kbuf, vbuf);
  conv_kernel<<<dim3(784,2), 256, 0, stream>>>(vbuf, wlT, bl, locl);
  attn_kernel<<<4096, 256, 0, stream>>>(q, kbuf, vbuf, attn);
  outproj_kernel<<<784, 256, 0, stream>>>(attn, locl, woT, bo, out);
}

// Round 2
// 460.564 us; speedup vs baseline: 1.5408x; 1.5408x over previous
//
#include <hip/hip_runtime.h>

typedef unsigned short ushort_t;
typedef __bf16  bf16x8 __attribute__((ext_vector_type(8)));
typedef float   f32x4  __attribute__((ext_vector_type(4)));
typedef unsigned short u16x8 __attribute__((ext_vector_type(8)));

#define MFMA16(a,b,c) __builtin_amdgcn_mfma_f32_16x16x32_bf16((a),(b),(c),0,0,0)

static __device__ __forceinline__ ushort_t f2bf(float f){
  union{float f; unsigned u;} x; x.f = f;
  unsigned r = x.u + 0x7fffu + ((x.u>>16)&1u);
  return (ushort_t)(r>>16);
}
static __device__ __forceinline__ float bf2f(ushort_t b){
  union{unsigned u; float f;} x; x.u = ((unsigned)b)<<16; return x.f;
}
static __device__ __forceinline__ bf16x8 ldg_bf8(const ushort_t* p, bool valid){
  u16x8 r = {0,0,0,0,0,0,0,0};
  if(valid) r = *(const u16x8*)p;
  return __builtin_bit_cast(bf16x8, r);
}
static __device__ __forceinline__ bf16x8 ldg_bf8u(const ushort_t* p){
  u16x8 r = *(const u16x8*)p;
  return __builtin_bit_cast(bf16x8, r);
}
static __device__ __forceinline__ bf16x8 lds_bf8(const ushort_t* p){
  u16x8 r = *(const u16x8*)p;
  return __builtin_bit_cast(bf16x8, r);
}
// async global->LDS, 16B per lane; lds dst must be wave-uniform base + lane*16
static __device__ __forceinline__ void gload_lds16(const ushort_t* g, ushort_t* l){
  __builtin_amdgcn_global_load_lds(
      (const __attribute__((address_space(1))) void*)g,
      (__attribute__((address_space(3))) void*)l, 16, 0, 0);
}

// ---------------------------------------------------------------- weights ^T
// qkvT[n(768)][k(192)], wlT[n(256)][tap(9)][k(256)], woT[n(192)][k(256)]
__global__ __launch_bounds__(256) void transpose_w_kernel(
    const float* __restrict__ Wq, const float* __restrict__ Wk,
    const float* __restrict__ Wv, const float* __restrict__ Wl,
    const float* __restrict__ Wo,
    ushort_t* __restrict__ qkvT, ushort_t* __restrict__ wlT,
    ushort_t* __restrict__ woT)
{
  int idx = blockIdx.x*256 + threadIdx.x;
  if(idx < 147456){
    int n = idx/192, kk = idx%192;
    const float* W = (n < 256) ? Wq : ((n < 512) ? Wk : Wv);
    qkvT[idx] = f2bf(W[kk*256 + (n & 255)]);
  } else if(idx < 147456 + 589824){
    int t2 = idx - 147456;
    int n = t2/2304, r = t2%2304;          // r = tap*256 + k
    wlT[t2] = f2bf(Wl[(size_t)r*256 + n]);
  } else if(idx < 147456 + 589824 + 49152){
    int t3 = idx - 737280;
    int col = t3/256, kk = t3%256;
    woT[t3] = f2bf(Wo[kk*192 + col]);
  }
}

// ---------------------------------------------------------------- qkv GEMM
// C[100352,256] = X[100352,192] @ W[192,256]  (per which in {q,k,v})
__global__ __launch_bounds__(256) void qkv_kernel(
    const float* __restrict__ x, const ushort_t* __restrict__ WT,
    ushort_t* __restrict__ q, ushort_t* __restrict__ kbuf,
    ushort_t* __restrict__ vbuf)
{
  __shared__ ushort_t aLds[128*192];
  const int m0 = blockIdx.x * 128;
  const int which = blockIdx.y;
  ushort_t* O = (which==0) ? q : ((which==1) ? kbuf : vbuf);
  const int tid = threadIdx.x;
  #pragma unroll
  for(int it=0; it<12; ++it){
    int c = tid + it*256;
    int row = c/24, cc = c%24;
    const float* src = x + (size_t)(m0+row)*192 + cc*8;
    float4 f0 = *(const float4*)src;
    float4 f1 = *(const float4*)(src+4);
    u16x8 o;
    o[0]=f2bf(f0.x); o[1]=f2bf(f0.y); o[2]=f2bf(f0.z); o[3]=f2bf(f0.w);
    o[4]=f2bf(f1.x); o[5]=f2bf(f1.y); o[6]=f2bf(f1.z); o[7]=f2bf(f1.w);
    int off = (row*192 + cc*8) ^ ((row&7)<<3);
    *(u16x8*)&aLds[off] = o;
  }
  __syncthreads();
  const int l = tid & 63, w = tid >> 6;
  const int wm = w>>1, wn = w&1, lr = l&15, g = l>>4;
  f32x4 acc[4][8];
  #pragma unroll
  for(int mi=0;mi<4;++mi)
    #pragma unroll
    for(int nj=0;nj<8;++nj){ f32x4 z={0.f,0.f,0.f,0.f}; acc[mi][nj]=z; }
  #pragma unroll
  for(int ks=0; ks<6; ++ks){
    bf16x8 af[4];
    #pragma unroll
    for(int mi=0;mi<4;++mi){
      int row = wm*64 + mi*16 + lr;
      af[mi] = lds_bf8(&aLds[(row*192 + ks*32 + g*8) ^ ((row&7)<<3)]);
    }
    #pragma unroll
    for(int nj=0;nj<8;++nj){
      int col = wn*128 + nj*16 + lr;
      bf16x8 bfr = ldg_bf8u(WT + (size_t)(which*256 + col)*192 + ks*32 + g*8);
      #pragma unroll
      for(int mi=0;mi<4;++mi) acc[mi][nj] = MFMA16(af[mi], bfr, acc[mi][nj]);
    }
  }
  #pragma unroll
  for(int mi=0;mi<4;++mi)
    #pragma unroll
    for(int nj=0;nj<8;++nj){
      int col = wn*128 + nj*16 + lr;
      #pragma unroll
      for(int i=0;i<4;++i){
        int row = wm*64 + mi*16 + g*4 + i;
        O[(size_t)(m0+row)*256 + col] = f2bf(acc[mi][nj][i]);
      }
    }
}

// ---------------------------------------------------------------- 3x3 conv
// implicit GEMM: local[p][n] = sum_{tap,k} v(p+shift(tap))[k] * WlT[n][tap][k] + b
// block: 128 px x 256 ch, 4 waves (2m x 2n), each 64px x 128ch.
// A: 256-px tile (64-px halo each side) x 32k staged per ks, reused by 9 taps.
// B: 3 taps (one dy row) x 256 x 32k staged per (ks,dy).
__global__ __launch_bounds__(256,2) void conv_kernel(
    const ushort_t* __restrict__ v, const ushort_t* __restrict__ WlT,
    const float* __restrict__ b_local, ushort_t* __restrict__ local_out)
{
  __shared__ ushort_t aLds[256*32];      // 16 KB
  __shared__ ushort_t bLds[3*256*32];    // 48 KB
  const int p0 = blockIdx.x*128;
  const int tid = threadIdx.x;
  const int l = tid&63, w=tid>>6, wm=w>>1, wn=w&1, lr=l&15, g=l>>4;

  // per-mi output pixel + 9-bit tap validity masks
  unsigned maskbits[4];
  int pxloc[4];
  #pragma unroll
  for(int mi=0;mi<4;++mi){
    int p = p0 + wm*64 + mi*16 + lr;
    int rem = p % 3136;
    int y = rem/56, x = rem%56;
    unsigned mb = 0;
    #pragma unroll
    for(int tap=0;tap<9;++tap){
      int dy = tap/3 - 1, dx = tap%3 - 1;
      if(((unsigned)(y+dy) < 56u) && ((unsigned)(x+dx) < 56u)) mb |= (1u<<tap);
    }
    maskbits[mi] = mb;
    pxloc[mi] = wm*64 + mi*16 + lr + 64;
  }

  f32x4 acc[4][8];
  #pragma unroll
  for(int mi=0;mi<4;++mi)
    #pragma unroll
    for(int nj=0;nj<8;++nj){ f32x4 z={0.f,0.f,0.f,0.f}; acc[mi][nj]=z; }

  for(int ks=0; ks<8; ++ks){
    __syncthreads();   // WAR: previous iteration's LDS reads complete
    // stage A: 256 px x 32 ch, swizzled source -> linear LDS
    #pragma unroll
    for(int r=0;r<4;++r){
      int c = tid + r*256;           // chunk id: px = c>>2, slot = c&3
      int px = c>>2, sl = c&3;
      int px_abs = p0 - 64 + px;
      px_abs = min(max(px_abs, 0), 100351);
      int chunk = sl ^ ((px>>1)&3);
      gload_lds16(v + (size_t)px_abs*256 + ks*32 + chunk*8,
                  aLds + (size_t)(w*64 + r*256)*8);
    }
    for(int dyi=0; dyi<3; ++dyi){
      if(dyi) __syncthreads();       // WAR for bLds
      // stage B: 3 dx-taps x 256 cols x 32 k
      #pragma unroll
      for(int r=0;r<12;++r){
        int dxi = r>>2, rr = r&3;
        int c = tid + rr*256;
        int col = c>>2, sl = c&3;
        int chunk = sl ^ ((col>>1)&3);
        gload_lds16(WlT + (size_t)col*2304 + (dyi*3+dxi)*256 + ks*32 + chunk*8,
                    bLds + (size_t)(dxi*8192 + (w*64 + rr*256)*8));
      }
      __syncthreads();               // RAW: drains global_load_lds (vmcnt0 before barrier)
      int dy = dyi - 1;
      #pragma unroll
      for(int dxi=0; dxi<3; ++dxi){
        int tap = dyi*3 + dxi;
        int shift = dy*56 + dxi - 1;
        bf16x8 af[4];
        #pragma unroll
        for(int mi=0;mi<4;++mi){
          int px = pxloc[mi] + shift;
          int sl = g ^ ((px>>1)&3);
          u16x8 rv = *(const u16x8*)&aLds[px*32 + sl*8];
          bool av = (maskbits[mi]>>tap)&1;
          if(!av){ u16x8 z = {0,0,0,0,0,0,0,0}; rv = z; }
          af[mi] = __builtin_bit_cast(bf16x8, rv);
        }
        #pragma unroll
        for(int nj=0;nj<8;++nj){
          int col = wn*128 + nj*16 + lr;
          int slb = g ^ ((col>>1)&3);
          bf16x8 bfr = lds_bf8(&bLds[dxi*8192 + col*32 + slb*8]);
          #pragma unroll
          for(int mi=0;mi<4;++mi) acc[mi][nj] = MFMA16(af[mi], bfr, acc[mi][nj]);
        }
      }
    }
  }
  // epilogue
  #pragma unroll
  for(int nj=0;nj<8;++nj){
    int col = wn*128 + nj*16 + lr;
    float bb = b_local[col];
    #pragma unroll
    for(int mi=0;mi<4;++mi)
      #pragma unroll
      for(int i=0;i<4;++i){
        int p = p0 + wm*64 + mi*16 + g*4 + i;
        local_out[(size_t)p*256 + col] = f2bf(acc[mi][nj][i] + bb);
      }
  }
}

// ---------------------------------------------------------------- attention
// one wave per (window, head); 49 padded to 64
__global__ __launch_bounds__(256) void attn_kernel(
    const ushort_t* __restrict__ q, const ushort_t* __restrict__ k,
    const ushort_t* __restrict__ v, ushort_t* __restrict__ out)
{
  __shared__ ushort_t pLds[4*64*64];
  __shared__ ushort_t vLds[4*32*64];
  const int tid = threadIdx.x;
  const int w = tid>>6, l = tid&63, lr = l&15, g = l>>4;
  const int gid = blockIdx.x*4 + w;
  const int win = gid>>3, head = gid&7;
  const int b = win>>6, rem = win&63, wy = rem>>3, wx = rem&7;
  const size_t base = (size_t)b*3136 + wy*7*56 + wx*7;
  ushort_t* pl = pLds + w*4096;
  ushort_t* vl = vLds + w*2048;
  {
    int p = l;
    bool valid = p < 49;
    const ushort_t* vp = v + (base + (p/7)*56 + (p%7))*256 + head*32;
    #pragma unroll
    for(int d0=0; d0<32; d0+=8){
      u16x8 rv = {0,0,0,0,0,0,0,0};
      if(valid) rv = *(const u16x8*)(vp + d0);
      #pragma unroll
      for(int j=0;j<8;++j){
        int d = d0+j;
        vl[(d*64 + p) ^ ((d&7)<<3)] = valid ? rv[j] : (ushort_t)0;
      }
    }
  }
  f32x4 dot[4][4];
  #pragma unroll
  for(int mi=0;mi<4;++mi)
    #pragma unroll
    for(int nj=0;nj<4;++nj){ f32x4 z={0.f,0.f,0.f,0.f}; dot[mi][nj]=z; }
  bf16x8 qf[4], kf[4];
  #pragma unroll
  for(int t=0;t<4;++t){
    int p = t*16 + lr; bool valid = p<49;
    size_t pix = base + (p/7)*56 + (p%7);
    qf[t] = ldg_bf8(q + pix*256 + head*32 + g*8, valid);
    kf[t] = ldg_bf8(k + pix*256 + head*32 + g*8, valid);
  }
  #pragma unroll
  for(int mi=0;mi<4;++mi)
    #pragma unroll
    for(int nj=0;nj<4;++nj)
      dot[mi][nj] = MFMA16(qf[mi], kf[nj], dot[mi][nj]);
  const float sc = 0.17677669529663687f * 1.4426950408889634f;
  float rs[4][4];
  #pragma unroll
  for(int mi=0;mi<4;++mi){
    #pragma unroll
    for(int i=0;i<4;++i){
      float m = -1e30f;
      #pragma unroll
      for(int nj=0;nj<4;++nj){
        int col = nj*16 + lr;
        if(col < 49) m = fmaxf(m, dot[mi][nj][i]);
      }
      m = fmaxf(m, __shfl_xor(m,1));
      m = fmaxf(m, __shfl_xor(m,2));
      m = fmaxf(m, __shfl_xor(m,4));
      m = fmaxf(m, __shfl_xor(m,8));
      float e[4]; float s = 0.f;
      #pragma unroll
      for(int nj=0;nj<4;++nj){
        int col = nj*16 + lr;
        e[nj] = (col < 49) ? exp2f((dot[mi][nj][i]-m)*sc) : 0.f;
        s += e[nj];
      }
      s += __shfl_xor(s,1); s += __shfl_xor(s,2);
      s += __shfl_xor(s,4); s += __shfl_xor(s,8);
      rs[mi][i] = s;
      int row = mi*16 + g*4 + i;
      #pragma unroll
      for(int nj=0;nj<4;++nj){
        int col = nj*16 + lr;
        pl[(row*64 + col) ^ ((row&7)<<3)] = f2bf(e[nj]);
      }
    }
  }
  __syncthreads();
  f32x4 o[4][2];
  #pragma unroll
  for(int mi=0;mi<4;++mi)
    #pragma unroll
    for(int nj=0;nj<2;++nj){ f32x4 z={0.f,0.f,0.f,0.f}; o[mi][nj]=z; }
  #pragma unroll
  for(int ks=0;ks<2;++ks){
    bf16x8 pa[4];
    #pragma unroll
    for(int mi=0;mi<4;++mi){
      int row = mi*16 + lr;
      pa[mi] = lds_bf8(&pl[(row*64 + ks*32 + g*8) ^ ((row&7)<<3)]);
    }
    #pragma unroll
    for(int nj=0;nj<2;++nj){
      int d = nj*16 + lr;
      bf16x8 vb = lds_bf8(&vl[(d*64 + ks*32 + g*8) ^ ((d&7)<<3)]);
      #pragma unroll
      for(int mi=0;mi<4;++mi) o[mi][nj] = MFMA16(pa[mi], vb, o[mi][nj]);
    }
  }
  #pragma unroll
  for(int mi=0;mi<4;++mi){
    #pragma unroll
    for(int i=0;i<4;++i){
      int row = mi*16 + g*4 + i;
      if(row < 49){
        size_t pix = base + (row/7)*56 + (row%7);
        float inv = 1.0f / rs[mi][i];
        #pragma unroll
        for(int nj=0;nj<2;++nj){
          out[pix*256 + head*32 + nj*16 + lr] = f2bf(o[mi][nj][i] * inv);
        }
      }
    }
  }
}

// ---------------------------------------------------------------- out proj
__global__ __launch_bounds__(256) void outproj_kernel(
    const ushort_t* __restrict__ attn, const ushort_t* __restrict__ local,
    const ushort_t* __restrict__ WoT, const float* __restrict__ b_out,
    float* __restrict__ out)
{
  __shared__ ushort_t aLds[128*256];
  const int m0 = blockIdx.x*128;
  const int tid = threadIdx.x;
  #pragma unroll
  for(int it=0; it<16; ++it){
    int c = tid + it*256;
    int row = c >> 5, cc = c & 31;
    size_t off = (size_t)(m0+row)*256 + cc*8;
    u16x8 a = *(const u16x8*)(attn + off);
    u16x8 bl = *(const u16x8*)(local + off);
    u16x8 o;
    #pragma unroll
    for(int j=0;j<8;++j) o[j] = f2bf(bf2f(a[j]) + bf2f(bl[j]));
    *(u16x8*)&aLds[(row*256 + cc*8) ^ ((row&7)<<3)] = o;
  }
  __syncthreads();
  const int l = tid&63, w = tid>>6, wm=w>>1, wn=w&1, lr=l&15, g=l>>4;
  f32x4 acc[4][6];
  #pragma unroll
  for(int mi=0;mi<4;++mi)
    #pragma unroll
    for(int nj=0;nj<6;++nj){ f32x4 z={0.f,0.f,0.f,0.f}; acc[mi][nj]=z; }
  #pragma unroll
  for(int ks=0;ks<8;++ks){
    bf16x8 af[4];
    #pragma unroll
    for(int mi=0;mi<4;++mi){
      int row = wm*64 + mi*16 + lr;
      af[mi] = lds_bf8(&aLds[(row*256 + ks*32 + g*8) ^ ((row&7)<<3)]);
    }
    #pragma unroll
    for(int nj=0;nj<6;++nj){
      int col = wn*96 + nj*16 + lr;
      bf16x8 bfr = ldg_bf8u(WoT + (size_t)col*256 + ks*32 + g*8);
      #pragma unroll
      for(int mi=0;mi<4;++mi) acc[mi][nj] = MFMA16(af[mi], bfr, acc[mi][nj]);
    }
  }
  #pragma unroll
  for(int nj=0;nj<6;++nj){
    int col = wn*96 + nj*16 + lr;
    float bb = b_out[col];
    #pragma unroll
    for(int mi=0;mi<4;++mi)
      #pragma unroll
      for(int i=0;i<4;++i){
        int row = wm*64 + mi*16 + g*4 + i;
        out[(size_t)(m0+row)*192 + col] = acc[mi][nj][i] + bb;
      }
  }
}

extern "C" void kernel_launch(void* const* d_in, const int* in_sizes, int n_in,
                              void* d_out, int out_size, void* d_ws, size_t ws_size,
                              hipStream_t stream)
{
  const float* x  = (const float*)d_in[0];
  const float* Wq = (const float*)d_in[1];
  const float* Wk = (const float*)d_in[2];
  const float* Wv = (const float*)d_in[3];
  const float* Wl = (const float*)d_in[4];
  const float* bl = (const float*)d_in[5];
  const float* Wo = (const float*)d_in[6];
  const float* bo = (const float*)d_in[7];
  float* out = (float*)d_out;
  char* ws = (char*)d_ws;
  ushort_t* q    = (ushort_t*)(ws);
  ushort_t* kbuf = (ushort_t*)(ws + 51380224);
  ushort_t* vbuf = (ushort_t*)(ws + 102760448);
  ushort_t* attn = (ushort_t*)(ws + 154140672);
  ushort_t* locl = (ushort_t*)(ws + 205520896);
  ushort_t* qkvT = (ushort_t*)(ws + 256901120);
  ushort_t* wlT  = (ushort_t*)(ws + 257196032);
  ushort_t* woT  = (ushort_t*)(ws + 258375680);

  transpose_w_kernel<<<3072, 256, 0, stream>>>(Wq, Wk, Wv, Wl, Wo, qkvT, wlT, woT);
  qkv_kernel<<<dim3(784,3), 256, 0, stream>>>(x, qkvT, q, kbuf, vbuf);
  conv_kernel<<<784, 256, 0, stream>>>(vbuf, wlT, bl, locl);
  attn_kernel<<<4096, 256, 0, stream>>>(q, kbuf, vbuf, attn);
  outproj_kernel<<<784, 256, 0, stream>>>(attn, locl, woT, bo, out);
}